// Round 13
// baseline (8681.768 us; speedup 1.0000x reference)
//
#include <hip/hip_runtime.h>
#include <hip/hip_bf16.h>

typedef unsigned int uint;
typedef unsigned short ushort;
typedef __fp16 half2_t __attribute__((ext_vector_type(2)));

// ---------- helpers ----------
__device__ __forceinline__ ushort f16b(float x){
  return __builtin_bit_cast(ushort, (_Float16)x);   // RNE
}
__device__ __forceinline__ uint pk_rne(float a, float b){
  return (uint)f16b(a) | ((uint)f16b(b) << 16);
}
// hi/lo double-f16 split; lo scaled by 2^11 so it stays in f16 normal range
// (raw residual ~|a|*2^-11 can be f16-subnormal -> dot2 FTZ risk).
// Recombine: value = hi + (lo * 2^-11)
__device__ __forceinline__ void pk_hl(float a, float b, uint& h, uint& l){
  _Float16 ha = (_Float16)a, hb = (_Float16)b;      // RNE
  float la = (a - (float)ha) * 2048.f;              // exact residual * 2^11
  float lb = (b - (float)hb) * 2048.f;
  h = (uint)__builtin_bit_cast(ushort, ha) | ((uint)__builtin_bit_cast(ushort, hb) << 16);
  l = pk_rne(la, lb);
}
__device__ __forceinline__ float fdot2(uint a, uint b, float c){
#if __has_builtin(__builtin_amdgcn_fdot2)
  return __builtin_amdgcn_fdot2(__builtin_bit_cast(half2_t, a),
                                __builtin_bit_cast(half2_t, b), c, false);
#else
  half2_t ha = __builtin_bit_cast(half2_t, a), hb = __builtin_bit_cast(half2_t, b);
  return c + (float)ha.x*(float)hb.x + (float)ha.y*(float)hb.y;
#endif
}
__device__ __forceinline__ float f16sel(uint p, uint hi){
  ushort us = hi ? (ushort)(p >> 16) : (ushort)(p & 0xffffu);
  return (float)__builtin_bit_cast(_Float16, us);
}
__device__ __forceinline__ float sigm(float x){ return 1.0f/(1.0f+__expf(-x)); }
__device__ __forceinline__ float tanh_(float x){
  x = fminf(fmaxf(x, -15.f), 15.f);
  float e = __expf(-2.f*x);
  return (1.f-e)/(1.f+e);
}
#define LO_SCALE (1.0f/2048.0f)

// B=128, C=8, N=256, T=64, Hd=256, L=2, F=32 ; OUTPUT = float32

// ---------- kPack: weights -> hi/lo f16 pairs, transposed ----------
// WdHi/WdLo    [256 kp][256 o]    k=[xi|attn]
// WcHi/WcLo    [256 kp][1024 j]   k=[xd|ht], j = gate*256+h (i,f,g,o)
// Wl1f         [512 k][32 f]      f32
// Wl2Hi/Wl2Lo  [272 kp][256 o]    k=relu([ct|ht|v]) (544)
// Wcrot        [64 b][32 tp][32 f] f16 pairs, ring-rotated
// WhT2         [128 np][256 h]    f16 pairs
// bcomb        [1024] = bih+bhh
__global__ void kPack(const float* __restrict__ Wd, const float* __restrict__ Wih,
                      const float* __restrict__ Whh, const float* __restrict__ Wl1,
                      const float* __restrict__ Wl2, const float* __restrict__ Wc,
                      const float* __restrict__ Wh,  const float* __restrict__ bih,
                      const float* __restrict__ bhh,
                      uint* __restrict__ WdHi, uint* __restrict__ WdLo,
                      uint* __restrict__ WcHi, uint* __restrict__ WcLo,
                      float* __restrict__ Wl1f,
                      uint* __restrict__ Wl2Hi, uint* __restrict__ Wl2Lo,
                      uint* __restrict__ Wcrot, uint* __restrict__ WhT2,
                      float* __restrict__ bcomb)
{
  const int NTOT = 65536*2 + 262144*2 + 16384 + 69632*2 + 65536 + 32768 + 1024;
  for (int idx = blockIdx.x*blockDim.x + threadIdx.x; idx < NTOT; idx += gridDim.x*blockDim.x){
    int i = idx;
    if (i < 131072){
      int j = (i < 65536) ? i : i - 65536;          // explicit (65536 IS pow2, keep style uniform)
      int kk = j>>8, o = j&255;
      float a = Wd[o*512+2*kk], b = Wd[o*512+2*kk+1];
      uint h, l; pk_hl(a, b, h, l);
      if (i < 65536) WdHi[j] = h; else WdLo[j] = l;
      continue; }
    i -= 131072;
    if (i < 524288){
      int j = (i < 262144) ? i : i - 262144;
      int kk = j>>10, jo = j&1023;
      float a, b;
      if (kk < 128){ a = Wih[jo*256+2*kk];        b = Wih[jo*256+2*kk+1]; }
      else         { a = Whh[jo*256+2*(kk-128)];  b = Whh[jo*256+2*(kk-128)+1]; }
      uint h, l; pk_hl(a, b, h, l);
      if (i < 262144) WcHi[j] = h; else WcLo[j] = l;
      continue; }
    i -= 524288;
    if (i < 16384){ int kk=i>>5, f=i&31; Wl1f[i] = Wl1[f*512+kk]; continue; }
    i -= 16384;
    if (i < 139264){
      int j = (i < 69632) ? i : i - 69632;          // FIX: 69632 is NOT pow2; & mask was wrong
      int kk = j>>8, o = j&255;
      float a = Wl2[o*544+2*kk], b = Wl2[o*544+2*kk+1];
      uint h, l; pk_hl(a, b, h, l);
      if (i < 69632) Wl2Hi[j] = h; else Wl2Lo[j] = l;
      continue; }
    i -= 139264;
    if (i < 65536){ int bb=i>>10, r=i&1023, ps=r>>5, f=r&31;
      float lo = Wc[f*64 + ((2*ps   - bb) & 63)];
      float hi = Wc[f*64 + ((2*ps+1 - bb) & 63)];
      Wcrot[i] = pk_rne(lo, hi); continue; }
    i -= 65536;
    if (i < 32768){ int np=i>>8, h=i&255;
      WhT2[i] = pk_rne(Wh[h*256+2*np], Wh[h*256+2*np+1]); continue; }
    i -= 32768;
    bcomb[i] = bih[i] + bhh[i];
  }
}

// ---------- K1a: yT[b][t][n] = relu(sum_c x[b,c,n,t]*wst[c] + bst) (f16) ----------
__global__ void k1a(const float* __restrict__ x, const float* __restrict__ wst,
                    const float* __restrict__ bst, ushort* __restrict__ yT)
{
  int b = blockIdx.x, tq = blockIdx.y, n = threadIdx.x;
  float acc[16];
  #pragma unroll
  for (int k=0;k<16;k++) acc[k]=0.f;
  for (int c=0;c<8;c++){
    const float4* xp = (const float4*)(x + ((size_t)((b*8+c)*256 + n)*64 + tq*16));
    float wc = wst[c];
    #pragma unroll
    for (int q=0;q<4;q++){
      float4 v = xp[q];
      acc[4*q+0] += v.x*wc; acc[4*q+1] += v.y*wc;
      acc[4*q+2] += v.z*wc; acc[4*q+3] += v.w*wc;
    }
  }
  float b0 = bst[0];
  #pragma unroll
  for (int k=0;k<16;k++){
    float v = fmaxf(acc[k]+b0, 0.f);
    yT[(size_t)(b*64 + tq*16 + k)*256 + n] = f16b(v);
  }
}

// ---------- K1b: xcon[b][t][h] = relu(sum_n y[b,n,t]*Wh[h,n] + bh[h]) ----------
__global__ void k1b(const uint* __restrict__ yT2, const uint* __restrict__ WhT2,
                    const float* __restrict__ bh, float* __restrict__ xcon)
{
  __shared__ uint yp[8192]; // [64 t][128 np]
  int b = blockIdx.x, tid = threadIdx.x;
  for (int i = tid; i < 8192; i += 256) yp[i] = yT2[(size_t)b*8192 + i];
  __syncthreads();
  int h = tid;
  float bias = bh[h];
  for (int tq=0;tq<4;tq++){
    float acc[16];
    #pragma unroll
    for (int k=0;k<16;k++) acc[k]=0.f;
    for (int np=0;np<128;np++){
      uint w2 = WhT2[np*256 + h];
      #pragma unroll
      for (int k=0;k<16;k++)
        acc[k] = fdot2(yp[(tq*16+k)*128 + np], w2, acc[k]);
    }
    #pragma unroll
    for (int k=0;k<16;k++)
      xcon[(size_t)(b*64 + tq*16 + k)*256 + h] = fmaxf(acc[k]+bias, 0.f);
  }
}

// ---------- K2: scan — one 256-thread block per batch element ----------
// GEMVs: w·x = (wh+wl/2048)·(xh+xl/2048) ≈ wh·xh + (wh·xl_s + wl_s·xh)/2048
// with hi in acc_hi, scaled-lo terms in acc_lo; f32-equivalent precision.
__global__ void TPALSTM_17205638987874_kernel(const float* __restrict__ xcon,
        const uint* __restrict__ WdHi, const uint* __restrict__ WdLo,
        const uint* __restrict__ WcHi, const uint* __restrict__ WcLo,
        const float* __restrict__ Wl1f,
        const uint* __restrict__ Wl2Hi, const uint* __restrict__ Wl2Lo,
        const uint* __restrict__ Wcrot,
        const float* __restrict__ bd, const float* __restrict__ bcomb,
        const float* __restrict__ bl1, const float* __restrict__ bl2,
        const float* __restrict__ bc, float* __restrict__ res)
{
  __shared__ uint  Hp[32][256];    // Hbuf ring, f16 pairs (phys slot s -> Hp[s>>1], lo/hi half)
  __shared__ uint  cvp[256][17];   // cv f16 pairs [o][fp]
  __shared__ float part[256];
  __shared__ float ht[256], ct[256], alpha[256];
  __shared__ uint  APRh[288], APRl[288];   // GEMV input pairs, hi / scaled-lo
  __shared__ uint  wpair[16];

  int b = blockIdx.x, tid = threadIdx.x;

  for (int i = tid; i < 32*256; i += 256) ((uint*)Hp)[i] = 0u;
  ht[tid]=0.f; ct[tid]=0.f;
  if (tid >= 128){ APRh[tid] = 0u; APRl[tid] = 0u; }  // attn_out = 0
  __syncthreads();

  int base = 0;
  for (int t=0;t<64;t++){
    // S1: xi = xcon_t
    if (tid < 128){
      const float* xr = xcon + (size_t)(b*64+t)*256;
      uint h,l; pk_hl(xr[2*tid], xr[2*tid+1], h, l);
      APRh[tid]=h; APRl[tid]=l;
    }
    __syncthreads();

    for (int l=0;l<2;l++){
      // S2: xd[o] = [xi|attn]@Wd^T + bd
      {
        float ahi=0.f, alo=0.f;
        const uint* wh = WdHi + tid;
        const uint* wl = WdLo + tid;
        #pragma unroll 4
        for (int kp=0;kp<256;kp++){
          uint Ah=APRh[kp], Al=APRl[kp];
          uint w=wh[0], v=wl[0];
          ahi = fdot2(Ah, w, ahi);
          alo = fdot2(Al, w, alo);
          alo = fdot2(Ah, v, alo);
          wh += 256; wl += 256;
        }
        part[tid] = ahi + alo*LO_SCALE + bd[tid];
      }
      __syncthreads();
      // S3: APR = [xd | ht raw]
      if (tid < 128){ uint h,l; pk_hl(part[2*tid], part[2*tid+1], h, l); APRh[tid]=h; APRl[tid]=l; }
      else { int j=tid-128; uint h,l; pk_hl(ht[2*j], ht[2*j+1], h, l); APRh[tid]=h; APRl[tid]=l; }
      __syncthreads();
      // S4: gates + LSTM cell, thread = h
      {
        float ih=0.f, il=0.f, fh=0.f, fl=0.f, gh=0.f, gl=0.f, oh=0.f, ol=0.f;
        const uint* wh = WcHi + tid;
        const uint* wl = WcLo + tid;
        #pragma unroll 2
        for (int kp=0;kp<256;kp++){
          uint Ah=APRh[kp], Al=APRl[kp];
          uint w0=wh[0], w1=wh[256], w2=wh[512], w3=wh[768];
          uint v0=wl[0], v1=wl[256], v2=wl[512], v3=wl[768];
          ih = fdot2(Ah,w0,ih); il = fdot2(Al,w0,il); il = fdot2(Ah,v0,il);
          fh = fdot2(Ah,w1,fh); fl = fdot2(Al,w1,fl); fl = fdot2(Ah,v1,fl);
          gh = fdot2(Ah,w2,gh); gl = fdot2(Al,w2,gl); gl = fdot2(Ah,v2,gl);
          oh = fdot2(Ah,w3,oh); ol = fdot2(Al,w3,ol); ol = fdot2(Ah,v3,ol);
          wh += 1024; wl += 1024;
        }
        float gi = sigm(ih + il*LO_SCALE + bcomb[tid]);
        float gf = sigm(fh + fl*LO_SCALE + bcomb[256+tid]);
        float gg = tanh_(gh + gl*LO_SCALE + bcomb[512+tid]);
        float go = sigm(oh + ol*LO_SCALE + bcomb[768+tid]);
        float c2 = gf*ct[tid] + gi*gg;
        float h2 = go*tanh_(c2);
        ct[tid]=c2; ht[tid]=h2;
      }
      __syncthreads();
      // S5+S6: APR = relu([ct|ht]); wl1 (tid<32, raw f32); Hbuf conv (all, f16)
      if (tid < 128){ uint h,l; pk_hl(fmaxf(ct[2*tid],0.f), fmaxf(ct[2*tid+1],0.f), h, l); APRh[tid]=h; APRl[tid]=l; }
      else { int j=tid-128; uint h,l; pk_hl(fmaxf(ht[2*j],0.f), fmaxf(ht[2*j+1],0.f), h, l); APRh[tid]=h; APRl[tid]=l; }
      if (tid < 32){
        float a=0.f;
        const float* w = Wl1f + tid;
        for (int k=0;k<256;k++) a += ct[k]*w[k*32];
        for (int k=0;k<256;k++) a += ht[k]*w[(256+k)*32];
        float wtot = a + bl1[tid];
        float wn = __shfl_xor(wtot,1);
        if (!(tid&1)) wpair[tid>>1] = pk_rne(wtot,wn);
      }
      {
        int rb = base & 63;
        const uint* wr = Wcrot + rb*1024;
        #pragma unroll
        for (int fh2=0; fh2<2; fh2++){
          float acc[16];
          #pragma unroll
          for (int j=0;j<16;j++) acc[j]=0.f;
          for (int ps=0;ps<32;ps++){
            uint hp = Hp[ps][tid];
            const uint* w = wr + ps*32 + fh2*16;
            #pragma unroll
            for (int j=0;j<16;j++) acc[j] = fdot2(hp, w[j], acc[j]);
          }
          #pragma unroll
          for (int jj=0;jj<8;jj++){
            int f0 = fh2*16 + 2*jj;
            cvp[tid][fh2*8+jj] = pk_rne(fmaxf(acc[2*jj]+bc[f0],0.f),
                                        fmaxf(acc[2*jj+1]+bc[f0+1],0.f));
          }
        }
      }
      __syncthreads();
      // S8: alpha[o] = sigmoid(sum_f cv*w)
      {
        float s=0.f;
        #pragma unroll
        for (int p=0;p<16;p++) s = fdot2(cvp[tid][p], wpair[p], s);
        alpha[tid] = sigm(s);
      }
      __syncthreads();
      // S9: v partials (8 o-chunks x 32 f)
      {
        int og = tid>>5, f = tid&31;
        uint hi = f&1; int fp=f>>1;
        float s=0.f;
        for (int oo=0;oo<32;oo++){
          int o = og*32+oo;
          s += alpha[o]*f16sel(cvp[o][fp], hi);
        }
        part[og*32+f] = s;
      }
      __syncthreads();
      // S10: v finish -> APR[256..271] (relu'd)
      if (tid<32){
        float v=0.f;
        #pragma unroll
        for (int g=0;g<8;g++) v += part[g*32+tid];
        float vn = __shfl_xor(v,1);
        if (!(tid&1)){
          uint h,l; pk_hl(fmaxf(v,0.f), fmaxf(vn,0.f), h, l);
          APRh[256+(tid>>1)]=h; APRl[256+(tid>>1)]=l;
        }
      }
      __syncthreads();
      // S12: new_ht[o] = relu([ct|ht|v])@Wl2^T + bl2
      {
        float ahi=0.f, alo=0.f;
        const uint* wh = Wl2Hi + tid;
        const uint* wl = Wl2Lo + tid;
        #pragma unroll 4
        for (int kp=0;kp<272;kp++){
          uint Ah=APRh[kp], Al=APRl[kp];
          uint w=wh[0], v=wl[0];
          ahi = fdot2(Ah, w, ahi);
          alo = fdot2(Al, w, alo);
          alo = fdot2(Ah, v, alo);
          wh += 256; wl += 256;
        }
        float nhv = ahi + alo*LO_SCALE + bl2[tid];
        part[tid] = nhv;
        if (l==1) res[(size_t)(t*128+b)*256 + tid] = nhv;
      }
      __syncthreads();
      // S13: APR = [ht raw | nh]
      if (tid<128){ uint h,l; pk_hl(ht[2*tid], ht[2*tid+1], h, l); APRh[tid]=h; APRl[tid]=l; }
      else { int j=tid-128; uint h,l; pk_hl(part[2*j], part[2*j+1], h, l); APRh[tid]=h; APRl[tid]=l; }
      __syncthreads();
      // S14: output[o] = [ht|nh]@Wd^T + bd
      {
        float ahi=0.f, alo=0.f;
        const uint* wh = WdHi + tid;
        const uint* wl = WdLo + tid;
        #pragma unroll 4
        for (int kp=0;kp<256;kp++){
          uint Ah=APRh[kp], Al=APRl[kp];
          uint w=wh[0], v=wl[0];
          ahi = fdot2(Ah, w, ahi);
          alo = fdot2(Al, w, alo);
          alo = fdot2(Ah, v, alo);
          wh += 256; wl += 256;
        }
        part[tid] = ahi + alo*LO_SCALE + bd[tid];
      }
      __syncthreads();
      // S15: next xi; Hbuf ring append relu(output). APR[128..255] keeps nh=attn.
      if (tid<128){
        float u0 = part[2*tid], u1 = part[2*tid+1];
        uint h,l; pk_hl(u0, u1, h, l);
        APRh[tid]=h; APRl[tid]=l;
        int s = base & 63, ps = s>>1; uint hi = (uint)(s&1);
        uint h0 = (uint)f16b(fmaxf(u0,0.f)), h1 = (uint)f16b(fmaxf(u1,0.f));
        int o0=2*tid, o1=o0+1;
        uint old0 = Hp[ps][o0], old1 = Hp[ps][o1];
        Hp[ps][o0] = hi ? ((old0&0xFFFFu)|(h0<<16)) : ((old0&0xFFFF0000u)|h0);
        Hp[ps][o1] = hi ? ((old1&0xFFFFu)|(h1<<16)) : ((old1&0xFFFF0000u)|h1);
      }
      __syncthreads();
      base++;
    }
  }
}

// ---------- K3: out[b,c,h,t] = relu(res[t,b,h])*wend[c] + bend[c]  (float32) ----------
__global__ void k3(const float* __restrict__ res, const float* __restrict__ wend,
                   const float* __restrict__ bend, float* __restrict__ out)
{
  __shared__ float r2[64][257];
  int b = blockIdx.x, tid = threadIdx.x;
  for (int i = tid; i < 16384; i += 256){
    int t = i >> 8, h = i & 255;
    r2[t][h] = fmaxf(res[(size_t)(t*128+b)*256 + h], 0.f);
  }
  __syncthreads();
  int tt = tid & 63, hg = tid >> 6;
  for (int c=0;c<8;c++){
    float we = wend[c], be = bend[c];
    for (int hh=0;hh<64;hh++){
      int h = hg*64 + hh;
      out[((size_t)(b*8+c)*256 + h)*64 + tt] = r2[tt][h]*we + be;
    }
  }
}

// ---------- launch ----------
extern "C" __attribute__((visibility("default"), used))
void kernel_launch(void* const* d_in, const int* in_sizes, int n_in,
                   void* d_out, int out_size, void* d_ws, size_t ws_size,
                   hipStream_t stream)
{
  const float* x    = (const float*)d_in[0];
  const float* wst  = (const float*)d_in[1];
  const float* bst  = (const float*)d_in[2];
  const float* Wh   = (const float*)d_in[3];
  const float* bh   = (const float*)d_in[4];
  const float* Wih  = (const float*)d_in[5];
  const float* Whh  = (const float*)d_in[6];
  const float* bih  = (const float*)d_in[7];
  const float* bhh  = (const float*)d_in[8];
  const float* Wd   = (const float*)d_in[9];
  const float* bd   = (const float*)d_in[10];
  const float* Wc   = (const float*)d_in[11];
  const float* bc   = (const float*)d_in[12];
  const float* Wl1  = (const float*)d_in[13];
  const float* bl1  = (const float*)d_in[14];
  const float* Wl2  = (const float*)d_in[15];
  const float* bl2  = (const float*)d_in[16];
  const float* wend = (const float*)d_in[17];
  const float* bend = (const float*)d_in[18];

  char* ws = (char*)d_ws;
  uint*  WdHi  = (uint*) (ws + 0);          // 262144 B
  uint*  WdLo  = (uint*) (ws + 262144);     // 262144 B
  uint*  WcHi  = (uint*) (ws + 524288);     // 1048576 B
  uint*  WcLo  = (uint*) (ws + 1572864);    // 1048576 B
  float* Wl1f  = (float*)(ws + 2621440);    // 65536 B
  uint*  Wl2Hi = (uint*) (ws + 2686976);    // 278528 B
  uint*  Wl2Lo = (uint*) (ws + 2965504);    // 278528 B
  uint*  Wcrot = (uint*) (ws + 3244032);    // 262144 B
  uint*  WhT2  = (uint*) (ws + 3506176);    // 131072 B
  float* bcomb = (float*)(ws + 3637248);    // 4096 B
  ushort* yT   = (ushort*)(ws + 3641344);   // 4194304 B
  float* xcon  = (float*)(ws + 7835648);    // 8388608 B
  float* res   = (float*)(ws + 16224256);   // 8388608 B -> end 24612864

  kPack<<<512, 256, 0, stream>>>(Wd, Wih, Whh, Wl1, Wl2, Wc, Wh, bih, bhh,
                                 WdHi, WdLo, WcHi, WcLo, Wl1f, Wl2Hi, Wl2Lo,
                                 Wcrot, WhT2, bcomb);
  k1a<<<dim3(128,4), 256, 0, stream>>>(x, wst, bst, yT);
  k1b<<<128, 256, 0, stream>>>((const uint*)yT, WhT2, bh, xcon);
  TPALSTM_17205638987874_kernel<<<128, 256, 0, stream>>>(xcon, WdHi, WdLo, WcHi, WcLo,
                                                         Wl1f, Wl2Hi, Wl2Lo, Wcrot,
                                                         bd, bcomb, bl1, bl2, bc, res);
  k3<<<128, 256, 0, stream>>>(res, wend, bend, (float*)d_out);
}

// Round 14
// 5914.647 us; speedup vs baseline: 1.4678x; 1.4678x over previous
//
#include <hip/hip_runtime.h>
#include <hip/hip_bf16.h>

typedef unsigned int uint;
typedef unsigned short ushort;
typedef __fp16 half2_t __attribute__((ext_vector_type(2)));

// ---------- helpers ----------
__device__ __forceinline__ ushort f16b(float x){
  return __builtin_bit_cast(ushort, (_Float16)x);   // RNE
}
__device__ __forceinline__ uint pk_rne(float a, float b){
  return (uint)f16b(a) | ((uint)f16b(b) << 16);
}
// hi/lo double-f16 split; lo scaled by 2^11 (stays f16-normal; avoids dot2 FTZ).
// value = hi + lo * 2^-11
__device__ __forceinline__ void pk_hl(float a, float b, uint& h, uint& l){
  _Float16 ha = (_Float16)a, hb = (_Float16)b;      // RNE
  float la = (a - (float)ha) * 2048.f;
  float lb = (b - (float)hb) * 2048.f;
  h = (uint)__builtin_bit_cast(ushort, ha) | ((uint)__builtin_bit_cast(ushort, hb) << 16);
  l = pk_rne(la, lb);
}
__device__ __forceinline__ float fdot2(uint a, uint b, float c){
#if __has_builtin(__builtin_amdgcn_fdot2)
  return __builtin_amdgcn_fdot2(__builtin_bit_cast(half2_t, a),
                                __builtin_bit_cast(half2_t, b), c, false);
#else
  half2_t ha = __builtin_bit_cast(half2_t, a), hb = __builtin_bit_cast(half2_t, b);
  return c + (float)ha.x*(float)hb.x + (float)ha.y*(float)hb.y;
#endif
}
__device__ __forceinline__ float f16sel(uint p, uint hi){
  ushort us = hi ? (ushort)(p >> 16) : (ushort)(p & 0xffffu);
  return (float)__builtin_bit_cast(_Float16, us);
}
__device__ __forceinline__ float sigm(float x){ return 1.0f/(1.0f+__expf(-x)); }
__device__ __forceinline__ float tanh_(float x){
  x = fminf(fmaxf(x, -15.f), 15.f);
  float e = __expf(-2.f*x);
  return (1.f-e)/(1.f+e);
}
#define LO_SCALE (1.0f/2048.0f)

// B=128, C=8, N=256, T=64, Hd=256, L=2, F=32 ; OUTPUT = float32

// ---------- kPack: weights -> vectorized hi/lo f16 layouts ----------
// Wd4   [128 kpp][256 o] uint4 {hi(kp=2kpp),lo,hi(2kpp+1),lo}   k=[xi|attn], kp = k-pair
// Wc4hi [256 kp][256 h]  uint4 {i,f,g,o gate hi};  Wc4lo same for lo.  k=[xd|ht]
// Wl24  [136 kpp][256 o] uint4 like Wd4            k=relu([ct|ht|v]) (544)
// Wl1f  [512 k][32 f] f32 ; Wcrot [64 b][32 tp][32 f] f16 pairs ; WhT2 [128 np][256 h]
__global__ void kPack(const float* __restrict__ Wd, const float* __restrict__ Wih,
                      const float* __restrict__ Whh, const float* __restrict__ Wl1,
                      const float* __restrict__ Wl2, const float* __restrict__ Wc,
                      const float* __restrict__ Wh,  const float* __restrict__ bih,
                      const float* __restrict__ bhh,
                      uint4* __restrict__ Wd4, uint4* __restrict__ Wc4hi,
                      uint4* __restrict__ Wc4lo, uint4* __restrict__ Wl24,
                      float* __restrict__ Wl1f, uint* __restrict__ Wcrot,
                      uint* __restrict__ WhT2, float* __restrict__ bcomb)
{
  const int NTOT = 32768 + 65536 + 34816 + 16384 + 65536 + 32768 + 1024; // 248832
  for (int idx = blockIdx.x*blockDim.x + threadIdx.x; idx < NTOT; idx += gridDim.x*blockDim.x){
    int i = idx;
    if (i < 32768){
      int kpp=i>>8, o=i&255, k0=4*kpp;
      uint h0,l0,h1,l1;
      pk_hl(Wd[o*512+k0],   Wd[o*512+k0+1], h0,l0);
      pk_hl(Wd[o*512+k0+2], Wd[o*512+k0+3], h1,l1);
      Wd4[i] = make_uint4(h0,l0,h1,l1); continue; }
    i -= 32768;
    if (i < 65536){
      int kp=i>>8, hh=i&255;
      uint wh[4], wl[4];
      #pragma unroll
      for (int gi=0; gi<4; gi++){
        int row = gi*256+hh;
        float a,b;
        if (kp<128){ a=Wih[row*256+2*kp]; b=Wih[row*256+2*kp+1]; }
        else       { a=Whh[row*256+2*(kp-128)]; b=Whh[row*256+2*(kp-128)+1]; }
        pk_hl(a,b,wh[gi],wl[gi]);
      }
      Wc4hi[i] = make_uint4(wh[0],wh[1],wh[2],wh[3]);
      Wc4lo[i] = make_uint4(wl[0],wl[1],wl[2],wl[3]); continue; }
    i -= 65536;
    if (i < 34816){
      int kpp=i>>8, o=i&255, k0=4*kpp;
      uint h0,l0,h1,l1;
      pk_hl(Wl2[o*544+k0],   Wl2[o*544+k0+1], h0,l0);
      pk_hl(Wl2[o*544+k0+2], Wl2[o*544+k0+3], h1,l1);
      Wl24[i] = make_uint4(h0,l0,h1,l1); continue; }
    i -= 34816;
    if (i < 16384){ int kk=i>>5, f=i&31; Wl1f[i] = Wl1[f*512+kk]; continue; }
    i -= 16384;
    if (i < 65536){ int bb=i>>10, r=i&1023, ps=r>>5, f=r&31;
      float lo = Wc[f*64 + ((2*ps   - bb) & 63)];
      float hi = Wc[f*64 + ((2*ps+1 - bb) & 63)];
      Wcrot[i] = pk_rne(lo, hi); continue; }
    i -= 65536;
    if (i < 32768){ int np=i>>8, h=i&255;
      WhT2[i] = pk_rne(Wh[h*256+2*np], Wh[h*256+2*np+1]); continue; }
    i -= 32768;
    bcomb[i] = bih[i] + bhh[i];
  }
}

// ---------- K1a ----------
__global__ void k1a(const float* __restrict__ x, const float* __restrict__ wst,
                    const float* __restrict__ bst, ushort* __restrict__ yT)
{
  int b = blockIdx.x, tq = blockIdx.y, n = threadIdx.x;
  float acc[16];
  #pragma unroll
  for (int k=0;k<16;k++) acc[k]=0.f;
  for (int c=0;c<8;c++){
    const float4* xp = (const float4*)(x + ((size_t)((b*8+c)*256 + n)*64 + tq*16));
    float wc = wst[c];
    #pragma unroll
    for (int q=0;q<4;q++){
      float4 v = xp[q];
      acc[4*q+0] += v.x*wc; acc[4*q+1] += v.y*wc;
      acc[4*q+2] += v.z*wc; acc[4*q+3] += v.w*wc;
    }
  }
  float b0 = bst[0];
  #pragma unroll
  for (int k=0;k<16;k++){
    float v = fmaxf(acc[k]+b0, 0.f);
    yT[(size_t)(b*64 + tq*16 + k)*256 + n] = f16b(v);
  }
}

// ---------- K1b ----------
__global__ void k1b(const uint* __restrict__ yT2, const uint* __restrict__ WhT2,
                    const float* __restrict__ bh, float* __restrict__ xcon)
{
  __shared__ uint yp[8192];
  int b = blockIdx.x, tid = threadIdx.x;
  for (int i = tid; i < 8192; i += 256) yp[i] = yT2[(size_t)b*8192 + i];
  __syncthreads();
  int h = tid;
  float bias = bh[h];
  for (int tq=0;tq<4;tq++){
    float acc[16];
    #pragma unroll
    for (int k=0;k<16;k++) acc[k]=0.f;
    for (int np=0;np<128;np++){
      uint w2 = WhT2[np*256 + h];
      #pragma unroll
      for (int k=0;k<16;k++)
        acc[k] = fdot2(yp[(tq*16+k)*128 + np], w2, acc[k]);
    }
    #pragma unroll
    for (int k=0;k<16;k++)
      xcon[(size_t)(b*64 + tq*16 + k)*256 + h] = fmaxf(acc[k]+bias, 0.f);
  }
}

// ---------- K2: scan — 512 threads/block, 2-way k-split GEMVs ----------
__global__ __launch_bounds__(512, 1)
void TPALSTM_17205638987874_kernel(const float* __restrict__ xcon,
        const uint4* __restrict__ Wd4, const uint4* __restrict__ Wc4hi,
        const uint4* __restrict__ Wc4lo, const uint4* __restrict__ Wl24,
        const float* __restrict__ Wl1f, const uint* __restrict__ Wcrot,
        const float* __restrict__ bd, const float* __restrict__ bcomb,
        const float* __restrict__ bl1, const float* __restrict__ bl2,
        const float* __restrict__ bc, float* __restrict__ res)
{
  __shared__ uint  Hp[32][256];            // Hbuf ring, f16 pairs
  __shared__ uint  cvp[256][17];           // cv f16 pairs [o][fp]
  __shared__ float gp[8][256];             // gate partials [g*4+gate][h]
  __shared__ float p2[2][256];             // GEMV partials (also 512-flat for S9)
  __shared__ float ht[256], ct[256], alpha[256], nh[256];
  __shared__ __align__(16) uint2 APR2[288];// {hi, lo_scaled} per k-pair
  __shared__ uint  wpair[16];

  int b = blockIdx.x, tid = threadIdx.x;
  int g = tid >> 8, o = tid & 255;

  for (int i = tid; i < 32*256; i += 512) ((uint*)Hp)[i] = 0u;
  if (tid < 256){ ht[tid]=0.f; ct[tid]=0.f; }
  if (tid >= 128 && tid < 256) APR2[tid] = make_uint2(0u,0u);  // attn_out = 0
  __syncthreads();

  int base = 0;
  for (int t=0;t<64;t++){
    // S1: xi = xcon_t
    if (tid < 128){
      const float* xr = xcon + (size_t)(b*64+t)*256;
      uint h,l; pk_hl(xr[2*tid], xr[2*tid+1], h, l);
      APR2[tid] = make_uint2(h,l);
    }
    __syncthreads();

    for (int l=0;l<2;l++){
      // S2: xd partials  (g: kpp in [g*64, g*64+64))
      {
        float ahi=0.f, alo=0.f;
        const uint4* wp = Wd4 + (size_t)(g*64)*256 + o;
        const uint4* ap = (const uint4*)(APR2 + g*128);
        #pragma unroll 4
        for (int kpp=0;kpp<64;kpp++){
          uint4 w = wp[0]; wp += 256;
          uint4 A = ap[kpp];
          ahi = fdot2(A.x, w.x, ahi); alo = fdot2(A.y, w.x, alo); alo = fdot2(A.x, w.y, alo);
          ahi = fdot2(A.z, w.z, ahi); alo = fdot2(A.w, w.z, alo); alo = fdot2(A.z, w.w, alo);
        }
        p2[g][o] = ahi + alo*LO_SCALE;
      }
      __syncthreads();
      // S3: APR = [xd | ht raw]
      if (tid < 128){
        float x0 = p2[0][2*tid]  + p2[1][2*tid]  + bd[2*tid];
        float x1 = p2[0][2*tid+1]+ p2[1][2*tid+1]+ bd[2*tid+1];
        uint h,l; pk_hl(x0,x1,h,l); APR2[tid]=make_uint2(h,l);
      } else if (tid < 256){
        int j=tid-128; uint h,l; pk_hl(ht[2*j], ht[2*j+1], h, l); APR2[tid]=make_uint2(h,l);
      }
      __syncthreads();
      // S4: gate partials  (g: kp in [g*128, g*128+128))
      {
        float ih=0.f,il=0.f,fh=0.f,fl=0.f,gh=0.f,gl=0.f,oh=0.f,ol=0.f;
        const uint4* whp = Wc4hi + (size_t)(g*128)*256 + o;
        const uint4* wlp = Wc4lo + (size_t)(g*128)*256 + o;
        #pragma unroll 2
        for (int kp=g*128; kp<g*128+128; kp++){
          uint4 w = whp[0]; whp += 256;
          uint4 v = wlp[0]; wlp += 256;
          uint2 A = APR2[kp];
          ih=fdot2(A.x,w.x,ih); il=fdot2(A.y,w.x,il); il=fdot2(A.x,v.x,il);
          fh=fdot2(A.x,w.y,fh); fl=fdot2(A.y,w.y,fl); fl=fdot2(A.x,v.y,fl);
          gh=fdot2(A.x,w.z,gh); gl=fdot2(A.y,w.z,gl); gl=fdot2(A.x,v.z,gl);
          oh=fdot2(A.x,w.w,oh); ol=fdot2(A.y,w.w,ol); ol=fdot2(A.x,v.w,ol);
        }
        gp[g*4+0][o]=ih+il*LO_SCALE; gp[g*4+1][o]=fh+fl*LO_SCALE;
        gp[g*4+2][o]=gh+gl*LO_SCALE; gp[g*4+3][o]=oh+ol*LO_SCALE;
      }
      __syncthreads();
      // cell (g==0 threads, h = o)
      if (g==0){
        float gi = sigm (gp[0][o]+gp[4][o]+bcomb[o]);
        float gf = sigm (gp[1][o]+gp[5][o]+bcomb[256+o]);
        float gg = tanh_(gp[2][o]+gp[6][o]+bcomb[512+o]);
        float go = sigm (gp[3][o]+gp[7][o]+bcomb[768+o]);
        float c2 = gf*ct[o] + gi*gg;
        float h2 = go*tanh_(c2);
        ct[o]=c2; ht[o]=h2;
      }
      __syncthreads();
      // S5+S6: APR=relu([ct|ht]) (tid<256); wl1 (tid 256..287); conv (all, fh=g)
      if (tid < 128){ uint h,l; pk_hl(fmaxf(ct[2*tid],0.f), fmaxf(ct[2*tid+1],0.f), h,l); APR2[tid]=make_uint2(h,l); }
      else if (tid < 256){ int j=tid-128; uint h,l; pk_hl(fmaxf(ht[2*j],0.f), fmaxf(ht[2*j+1],0.f), h,l); APR2[tid]=make_uint2(h,l); }
      else if (tid < 288){
        int f = tid-256;
        float a=0.f;
        const float* w = Wl1f + f;
        for (int k=0;k<256;k++) a += ct[k]*w[k*32];
        for (int k=0;k<256;k++) a += ht[k]*w[(256+k)*32];
        float wtot = a + bl1[f];
        float wn = __shfl_xor(wtot,1);
        if (!(f&1)) wpair[f>>1] = pk_rne(wtot,wn);
      }
      {
        int rb = base & 63;
        const uint* wr = Wcrot + rb*1024 + g*16;
        float acc[16];
        #pragma unroll
        for (int j=0;j<16;j++) acc[j]=0.f;
        for (int ps=0;ps<32;ps++){
          uint hp = Hp[ps][o];
          const uint* w = wr + ps*32;
          #pragma unroll
          for (int j=0;j<16;j++) acc[j] = fdot2(hp, w[j], acc[j]);
        }
        #pragma unroll
        for (int jj=0;jj<8;jj++){
          int f0 = g*16 + 2*jj;
          cvp[o][g*8+jj] = pk_rne(fmaxf(acc[2*jj]+bc[f0],0.f),
                                  fmaxf(acc[2*jj+1]+bc[f0+1],0.f));
        }
      }
      __syncthreads();
      // S8: alpha
      if (tid < 256){
        float s=0.f;
        #pragma unroll
        for (int p=0;p<16;p++) s = fdot2(cvp[tid][p], wpair[p], s);
        alpha[tid] = sigm(s);
      }
      __syncthreads();
      // S9: v partials (16 o-chunks x 32 f)
      {
        int og = tid>>5, f = tid&31;
        uint hi = f&1; int fp=f>>1;
        float s=0.f;
        #pragma unroll
        for (int oo=0;oo<16;oo++){
          int oa = og*16+oo;
          s += alpha[oa]*f16sel(cvp[oa][fp], hi);
        }
        ((float*)p2)[og*32+f] = s;
      }
      __syncthreads();
      // S10: v finish -> APR[256..271]
      if (tid<32){
        float v=0.f;
        #pragma unroll
        for (int q=0;q<16;q++) v += ((float*)p2)[q*32+tid];
        float vn = __shfl_xor(v,1);
        if (!(tid&1)){
          uint h,l; pk_hl(fmaxf(v,0.f), fmaxf(vn,0.f), h,l);
          APR2[256+(tid>>1)]=make_uint2(h,l);
        }
      }
      __syncthreads();
      // S12: Wl2 partials  (g: kpp in [g*68, g*68+68))
      {
        float ahi=0.f, alo=0.f;
        const uint4* wp = Wl24 + (size_t)(g*68)*256 + o;
        const uint4* ap = (const uint4*)(APR2 + g*136);
        #pragma unroll 4
        for (int kpp=0;kpp<68;kpp++){
          uint4 w = wp[0]; wp += 256;
          uint4 A = ap[kpp];
          ahi = fdot2(A.x, w.x, ahi); alo = fdot2(A.y, w.x, alo); alo = fdot2(A.x, w.y, alo);
          ahi = fdot2(A.z, w.z, ahi); alo = fdot2(A.w, w.z, alo); alo = fdot2(A.z, w.w, alo);
        }
        p2[g][o] = ahi + alo*LO_SCALE;
      }
      __syncthreads();
      // S12b: nh + res write
      if (g==0){
        float nhv = p2[0][o]+p2[1][o]+bl2[o];
        nh[o] = nhv;
        if (l==1) res[(size_t)(t*128+b)*256 + o] = nhv;
      }
      __syncthreads();
      // S13: APR = [ht raw | nh]
      if (tid<128){ uint h,l; pk_hl(ht[2*tid], ht[2*tid+1], h,l); APR2[tid]=make_uint2(h,l); }
      else if (tid<256){ int j=tid-128; uint h,l; pk_hl(nh[2*j], nh[2*j+1], h,l); APR2[tid]=make_uint2(h,l); }
      __syncthreads();
      // S14: output partials
      {
        float ahi=0.f, alo=0.f;
        const uint4* wp = Wd4 + (size_t)(g*64)*256 + o;
        const uint4* ap = (const uint4*)(APR2 + g*128);
        #pragma unroll 4
        for (int kpp=0;kpp<64;kpp++){
          uint4 w = wp[0]; wp += 256;
          uint4 A = ap[kpp];
          ahi = fdot2(A.x, w.x, ahi); alo = fdot2(A.y, w.x, alo); alo = fdot2(A.x, w.y, alo);
          ahi = fdot2(A.z, w.z, ahi); alo = fdot2(A.w, w.z, alo); alo = fdot2(A.z, w.w, alo);
        }
        p2[g][o] = ahi + alo*LO_SCALE;
      }
      __syncthreads();
      // S15: next xi pairs; Hbuf ring append relu(output). APR[128..255] keeps nh.
      if (tid<128){
        float u0 = p2[0][2*tid]  + p2[1][2*tid]  + bd[2*tid];
        float u1 = p2[0][2*tid+1]+ p2[1][2*tid+1]+ bd[2*tid+1];
        uint h,l; pk_hl(u0, u1, h, l);
        APR2[tid]=make_uint2(h,l);
        int s = base & 63, ps = s>>1; uint hb = (uint)(s&1);
        uint h0 = (uint)f16b(fmaxf(u0,0.f)), h1 = (uint)f16b(fmaxf(u1,0.f));
        int o0=2*tid, o1=o0+1;
        uint old0 = Hp[ps][o0], old1 = Hp[ps][o1];
        Hp[ps][o0] = hb ? ((old0&0xFFFFu)|(h0<<16)) : ((old0&0xFFFF0000u)|h0);
        Hp[ps][o1] = hb ? ((old1&0xFFFFu)|(h1<<16)) : ((old1&0xFFFF0000u)|h1);
      }
      __syncthreads();
      base++;
    }
  }
}

// ---------- K3: out[b,c,h,t] = relu(res[t,b,h])*wend[c] + bend[c]  (float32) ----------
__global__ void k3(const float* __restrict__ res, const float* __restrict__ wend,
                   const float* __restrict__ bend, float* __restrict__ out)
{
  __shared__ float r2[64][257];
  int b = blockIdx.x, tid = threadIdx.x;
  for (int i = tid; i < 16384; i += 256){
    int t = i >> 8, h = i & 255;
    r2[t][h] = fmaxf(res[(size_t)(t*128+b)*256 + h], 0.f);
  }
  __syncthreads();
  int tt = tid & 63, hg = tid >> 6;
  for (int c=0;c<8;c++){
    float we = wend[c], be = bend[c];
    for (int hh=0;hh<64;hh++){
      int h = hg*64 + hh;
      out[((size_t)(b*8+c)*256 + h)*64 + tt] = r2[tt][h]*we + be;
    }
  }
}

// ---------- launch ----------
extern "C" __attribute__((visibility("default"), used))
void kernel_launch(void* const* d_in, const int* in_sizes, int n_in,
                   void* d_out, int out_size, void* d_ws, size_t ws_size,
                   hipStream_t stream)
{
  const float* x    = (const float*)d_in[0];
  const float* wst  = (const float*)d_in[1];
  const float* bst  = (const float*)d_in[2];
  const float* Wh   = (const float*)d_in[3];
  const float* bh   = (const float*)d_in[4];
  const float* Wih  = (const float*)d_in[5];
  const float* Whh  = (const float*)d_in[6];
  const float* bih  = (const float*)d_in[7];
  const float* bhh  = (const float*)d_in[8];
  const float* Wd   = (const float*)d_in[9];
  const float* bd   = (const float*)d_in[10];
  const float* Wc   = (const float*)d_in[11];
  const float* bc   = (const float*)d_in[12];
  const float* Wl1  = (const float*)d_in[13];
  const float* bl1  = (const float*)d_in[14];
  const float* Wl2  = (const float*)d_in[15];
  const float* bl2  = (const float*)d_in[16];
  const float* wend = (const float*)d_in[17];
  const float* bend = (const float*)d_in[18];

  char* ws = (char*)d_ws;
  uint4* Wd4   = (uint4*)(ws + 0);          // 524288 B
  uint4* Wc4hi = (uint4*)(ws + 524288);     // 1048576 B
  uint4* Wc4lo = (uint4*)(ws + 1572864);    // 1048576 B
  uint4* Wl24  = (uint4*)(ws + 2621440);    // 557056 B
  float* Wl1f  = (float*)(ws + 3178496);    // 65536 B
  uint*  Wcrot = (uint*) (ws + 3244032);    // 262144 B
  uint*  WhT2  = (uint*) (ws + 3506176);    // 131072 B
  float* bcomb = (float*)(ws + 3637248);    // 4096 B
  ushort* yT   = (ushort*)(ws + 3641344);   // 4194304 B
  float* xcon  = (float*)(ws + 7835648);    // 8388608 B
  float* res   = (float*)(ws + 16224256);   // 8388608 B -> end 24612864

  kPack<<<512, 256, 0, stream>>>(Wd, Wih, Whh, Wl1, Wl2, Wc, Wh, bih, bhh,
                                 Wd4, Wc4hi, Wc4lo, Wl24, Wl1f, Wcrot, WhT2, bcomb);
  k1a<<<dim3(128,4), 256, 0, stream>>>(x, wst, bst, yT);
  k1b<<<128, 256, 0, stream>>>((const uint*)yT, WhT2, bh, xcon);
  TPALSTM_17205638987874_kernel<<<128, 512, 0, stream>>>(xcon, Wd4, Wc4hi, Wc4lo, Wl24,
                                                         Wl1f, Wcrot, bd, bcomb, bl1, bl2, bc, res);
  k3<<<128, 256, 0, stream>>>(res, wend, bend, (float*)d_out);
}

// Round 15
// 5108.026 us; speedup vs baseline: 1.6996x; 1.1579x over previous
//
#include <hip/hip_runtime.h>
#include <hip/hip_bf16.h>

typedef unsigned int uint;
typedef unsigned short ushort;
typedef __fp16 half2_t __attribute__((ext_vector_type(2)));

// ---------- helpers ----------
__device__ __forceinline__ ushort f16b(float x){
  return __builtin_bit_cast(ushort, (_Float16)x);   // RNE
}
__device__ __forceinline__ uint pk_rne(float a, float b){
  return (uint)f16b(a) | ((uint)f16b(b) << 16);
}
// hi/lo double-f16 split; lo scaled by 2^11 (stays f16-normal; avoids dot2 FTZ).
// value = hi + lo * 2^-11
__device__ __forceinline__ void pk_hl(float a, float b, uint& h, uint& l){
  _Float16 ha = (_Float16)a, hb = (_Float16)b;      // RNE
  float la = (a - (float)ha) * 2048.f;
  float lb = (b - (float)hb) * 2048.f;
  h = (uint)__builtin_bit_cast(ushort, ha) | ((uint)__builtin_bit_cast(ushort, hb) << 16);
  l = pk_rne(la, lb);
}
__device__ __forceinline__ float fdot2(uint a, uint b, float c){
#if __has_builtin(__builtin_amdgcn_fdot2)
  return __builtin_amdgcn_fdot2(__builtin_bit_cast(half2_t, a),
                                __builtin_bit_cast(half2_t, b), c, false);
#else
  half2_t ha = __builtin_bit_cast(half2_t, a), hb = __builtin_bit_cast(half2_t, b);
  return c + (float)ha.x*(float)hb.x + (float)ha.y*(float)hb.y;
#endif
}
__device__ __forceinline__ float f16sel(uint p, uint hi){
  ushort us = hi ? (ushort)(p >> 16) : (ushort)(p & 0xffffu);
  return (float)__builtin_bit_cast(_Float16, us);
}
__device__ __forceinline__ float sigm(float x){ return 1.0f/(1.0f+__expf(-x)); }
__device__ __forceinline__ float tanh_(float x){
  x = fminf(fmaxf(x, -15.f), 15.f);
  float e = __expf(-2.f*x);
  return (1.f-e)/(1.f+e);
}
#define LO_SCALE (1.0f/2048.0f)

// B=128, C=8, N=256, T=64, Hd=256, L=2, F=32 ; OUTPUT = float32

// ---------- kPack (unchanged layouts) ----------
// Wd4   [128 kpp][256 o] uint4 {hi,lo,hi,lo}  k=[xi|attn]
// Wc4hi [256 kp][256 h]  uint4 gate-hi ; Wc4lo gate-lo.  k=[xd|ht]
// Wl24  [136 kpp][256 o] uint4 like Wd4       k=relu([ct|ht|v]) (544)
// Wl1f [512][32] f32 ; Wcrot [64][32][32] f16 pairs ; WhT2 [128][256]
__global__ void kPack(const float* __restrict__ Wd, const float* __restrict__ Wih,
                      const float* __restrict__ Whh, const float* __restrict__ Wl1,
                      const float* __restrict__ Wl2, const float* __restrict__ Wc,
                      const float* __restrict__ Wh,  const float* __restrict__ bih,
                      const float* __restrict__ bhh,
                      uint4* __restrict__ Wd4, uint4* __restrict__ Wc4hi,
                      uint4* __restrict__ Wc4lo, uint4* __restrict__ Wl24,
                      float* __restrict__ Wl1f, uint* __restrict__ Wcrot,
                      uint* __restrict__ WhT2, float* __restrict__ bcomb)
{
  const int NTOT = 32768 + 65536 + 34816 + 16384 + 65536 + 32768 + 1024;
  for (int idx = blockIdx.x*blockDim.x + threadIdx.x; idx < NTOT; idx += gridDim.x*blockDim.x){
    int i = idx;
    if (i < 32768){
      int kpp=i>>8, o=i&255, k0=4*kpp;
      uint h0,l0,h1,l1;
      pk_hl(Wd[o*512+k0],   Wd[o*512+k0+1], h0,l0);
      pk_hl(Wd[o*512+k0+2], Wd[o*512+k0+3], h1,l1);
      Wd4[i] = make_uint4(h0,l0,h1,l1); continue; }
    i -= 32768;
    if (i < 65536){
      int kp=i>>8, hh=i&255;
      uint wh[4], wl[4];
      #pragma unroll
      for (int gi=0; gi<4; gi++){
        int row = gi*256+hh;
        float a,b;
        if (kp<128){ a=Wih[row*256+2*kp]; b=Wih[row*256+2*kp+1]; }
        else       { a=Whh[row*256+2*(kp-128)]; b=Whh[row*256+2*(kp-128)+1]; }
        pk_hl(a,b,wh[gi],wl[gi]);
      }
      Wc4hi[i] = make_uint4(wh[0],wh[1],wh[2],wh[3]);
      Wc4lo[i] = make_uint4(wl[0],wl[1],wl[2],wl[3]); continue; }
    i -= 65536;
    if (i < 34816){
      int kpp=i>>8, o=i&255, k0=4*kpp;
      uint h0,l0,h1,l1;
      pk_hl(Wl2[o*544+k0],   Wl2[o*544+k0+1], h0,l0);
      pk_hl(Wl2[o*544+k0+2], Wl2[o*544+k0+3], h1,l1);
      Wl24[i] = make_uint4(h0,l0,h1,l1); continue; }
    i -= 34816;
    if (i < 16384){ int kk=i>>5, f=i&31; Wl1f[i] = Wl1[f*512+kk]; continue; }
    i -= 16384;
    if (i < 65536){ int bb=i>>10, r=i&1023, ps=r>>5, f=r&31;
      float lo = Wc[f*64 + ((2*ps   - bb) & 63)];
      float hi = Wc[f*64 + ((2*ps+1 - bb) & 63)];
      Wcrot[i] = pk_rne(lo, hi); continue; }
    i -= 65536;
    if (i < 32768){ int np=i>>8, h=i&255;
      WhT2[i] = pk_rne(Wh[h*256+2*np], Wh[h*256+2*np+1]); continue; }
    i -= 32768;
    bcomb[i] = bih[i] + bhh[i];
  }
}

// ---------- K1a ----------
__global__ void k1a(const float* __restrict__ x, const float* __restrict__ wst,
                    const float* __restrict__ bst, ushort* __restrict__ yT)
{
  int b = blockIdx.x, tq = blockIdx.y, n = threadIdx.x;
  float acc[16];
  #pragma unroll
  for (int k=0;k<16;k++) acc[k]=0.f;
  for (int c=0;c<8;c++){
    const float4* xp = (const float4*)(x + ((size_t)((b*8+c)*256 + n)*64 + tq*16));
    float wc = wst[c];
    #pragma unroll
    for (int q=0;q<4;q++){
      float4 v = xp[q];
      acc[4*q+0] += v.x*wc; acc[4*q+1] += v.y*wc;
      acc[4*q+2] += v.z*wc; acc[4*q+3] += v.w*wc;
    }
  }
  float b0 = bst[0];
  #pragma unroll
  for (int k=0;k<16;k++){
    float v = fmaxf(acc[k]+b0, 0.f);
    yT[(size_t)(b*64 + tq*16 + k)*256 + n] = f16b(v);
  }
}

// ---------- K1b ----------
__global__ void k1b(const uint* __restrict__ yT2, const uint* __restrict__ WhT2,
                    const float* __restrict__ bh, float* __restrict__ xcon)
{
  __shared__ uint yp[8192];
  int b = blockIdx.x, tid = threadIdx.x;
  for (int i = tid; i < 8192; i += 256) yp[i] = yT2[(size_t)b*8192 + i];
  __syncthreads();
  int h = tid;
  float bias = bh[h];
  for (int tq=0;tq<4;tq++){
    float acc[16];
    #pragma unroll
    for (int k=0;k<16;k++) acc[k]=0.f;
    for (int np=0;np<128;np++){
      uint w2 = WhT2[np*256 + h];
      #pragma unroll
      for (int k=0;k<16;k++)
        acc[k] = fdot2(yp[(tq*16+k)*128 + np], w2, acc[k]);
    }
    #pragma unroll
    for (int k=0;k<16;k++)
      xcon[(size_t)(b*64 + tq*16 + k)*256 + h] = fmaxf(acc[k]+bias, 0.f);
  }
}

// ---------- K2: scan — 1024 threads/block, 4-way k-split GEMVs ----------
__global__ __launch_bounds__(1024, 1)
void TPALSTM_17205638987874_kernel(const float* __restrict__ xcon,
        const uint4* __restrict__ Wd4, const uint4* __restrict__ Wc4hi,
        const uint4* __restrict__ Wc4lo, const uint4* __restrict__ Wl24,
        const float* __restrict__ Wl1f, const uint* __restrict__ Wcrot,
        const float* __restrict__ bd, const float* __restrict__ bcomb,
        const float* __restrict__ bl1, const float* __restrict__ bl2,
        const float* __restrict__ bc, float* __restrict__ res)
{
  __shared__ uint  Hp[32][256];            // Hbuf ring, f16 pairs
  __shared__ uint  cvp[256][17];           // cv f16 pairs [o][fp]
  __shared__ float gp[16][256];            // gate partials [g*4+gate][h]; reused as 1024-float vpart
  __shared__ float p4[4][256];             // 4-way GEMV partials
  __shared__ float ht[256], ct[256], alpha[256];
  __shared__ __align__(16) uint2 APR2[288];// {hi, lo_scaled} per k-pair
  __shared__ uint  wpair[16];

  int b = blockIdx.x, tid = threadIdx.x;
  int g = tid >> 8, o = tid & 255;

  for (int i = tid; i < 32*256; i += 1024) ((uint*)Hp)[i] = 0u;
  if (tid < 256){ ht[tid]=0.f; ct[tid]=0.f; }
  if (tid >= 128 && tid < 256) APR2[tid] = make_uint2(0u,0u);  // attn_out = 0
  __syncthreads();

  int base = 0;
  for (int t=0;t<64;t++){
    // S1: xi = xcon_t
    if (tid < 128){
      const float* xr = xcon + (size_t)(b*64+t)*256;
      uint h,l; pk_hl(xr[2*tid], xr[2*tid+1], h, l);
      APR2[tid] = make_uint2(h,l);
    }
    __syncthreads();

    for (int l=0;l<2;l++){
      // S2: xd partials  (g: kpp in [g*32, g*32+32))
      {
        float ahi=0.f, alo=0.f;
        const uint4* wp = Wd4 + (size_t)(g*32)*256 + o;
        const uint4* ap = (const uint4*)(APR2 + g*64);
        #pragma unroll 4
        for (int kpp=0;kpp<32;kpp++){
          uint4 w = wp[0]; wp += 256;
          uint4 A = ap[kpp];
          ahi = fdot2(A.x, w.x, ahi); alo = fdot2(A.y, w.x, alo); alo = fdot2(A.x, w.y, alo);
          ahi = fdot2(A.z, w.z, ahi); alo = fdot2(A.w, w.z, alo); alo = fdot2(A.z, w.w, alo);
        }
        p4[g][o] = ahi + alo*LO_SCALE;
      }
      __syncthreads();
      // S3: APR = [xd | ht raw]
      if (tid < 128){
        int o0=2*tid, o1=o0+1;
        float x0 = p4[0][o0]+p4[1][o0]+p4[2][o0]+p4[3][o0]+bd[o0];
        float x1 = p4[0][o1]+p4[1][o1]+p4[2][o1]+p4[3][o1]+bd[o1];
        uint h,l; pk_hl(x0,x1,h,l); APR2[tid]=make_uint2(h,l);
      } else if (tid < 256){
        int j=tid-128; uint h,l; pk_hl(ht[2*j], ht[2*j+1], h, l); APR2[tid]=make_uint2(h,l);
      }
      __syncthreads();
      // S4: gate partials  (g: kp in [g*64, g*64+64))
      {
        float ih=0.f,il=0.f,fh=0.f,fl=0.f,gh=0.f,gl=0.f,oh=0.f,ol=0.f;
        const uint4* whp = Wc4hi + (size_t)(g*64)*256 + o;
        const uint4* wlp = Wc4lo + (size_t)(g*64)*256 + o;
        #pragma unroll 2
        for (int kp=g*64; kp<g*64+64; kp++){
          uint4 w = whp[0]; whp += 256;
          uint4 v = wlp[0]; wlp += 256;
          uint2 A = APR2[kp];
          ih=fdot2(A.x,w.x,ih); il=fdot2(A.y,w.x,il); il=fdot2(A.x,v.x,il);
          fh=fdot2(A.x,w.y,fh); fl=fdot2(A.y,w.y,fl); fl=fdot2(A.x,v.y,fl);
          gh=fdot2(A.x,w.z,gh); gl=fdot2(A.y,w.z,gl); gl=fdot2(A.x,v.z,gl);
          oh=fdot2(A.x,w.w,oh); ol=fdot2(A.y,w.w,ol); ol=fdot2(A.x,v.w,ol);
        }
        gp[g*4+0][o]=ih+il*LO_SCALE; gp[g*4+1][o]=fh+fl*LO_SCALE;
        gp[g*4+2][o]=gh+gl*LO_SCALE; gp[g*4+3][o]=oh+ol*LO_SCALE;
      }
      __syncthreads();
      // cell (g==0 threads, h = o)
      if (g==0){
        float gi = sigm (gp[0][o]+gp[4][o]+gp[8][o] +gp[12][o]+bcomb[o]);
        float gf = sigm (gp[1][o]+gp[5][o]+gp[9][o] +gp[13][o]+bcomb[256+o]);
        float gg = tanh_(gp[2][o]+gp[6][o]+gp[10][o]+gp[14][o]+bcomb[512+o]);
        float go = sigm (gp[3][o]+gp[7][o]+gp[11][o]+gp[15][o]+bcomb[768+o]);
        float c2 = gf*ct[o] + gi*gg;
        float h2 = go*tanh_(c2);
        ct[o]=c2; ht[o]=h2;
      }
      __syncthreads();
      // S5+S6: APR=relu([ct|ht]); wl1 (g==2, o<32); conv (g<2, fh=g)
      if (tid < 128){ uint h,l; pk_hl(fmaxf(ct[2*tid],0.f), fmaxf(ct[2*tid+1],0.f), h,l); APR2[tid]=make_uint2(h,l); }
      else if (tid < 256){ int j=tid-128; uint h,l; pk_hl(fmaxf(ht[2*j],0.f), fmaxf(ht[2*j+1],0.f), h,l); APR2[tid]=make_uint2(h,l); }
      if (g==2 && o < 32){
        int f = o;
        float a=0.f;
        const float* w = Wl1f + f;
        for (int k=0;k<256;k++) a += ct[k]*w[k*32];
        for (int k=0;k<256;k++) a += ht[k]*w[(256+k)*32];
        float wtot = a + bl1[f];
        float wn = __shfl_xor(wtot,1);
        if (!(f&1)) wpair[f>>1] = pk_rne(wtot,wn);
      }
      if (g < 2){
        int rb = base & 63;
        const uint* wr = Wcrot + rb*1024 + g*16;
        float acc[16];
        #pragma unroll
        for (int j=0;j<16;j++) acc[j]=0.f;
        for (int ps=0;ps<32;ps++){
          uint hp = Hp[ps][o];
          const uint* w = wr + ps*32;
          #pragma unroll
          for (int j=0;j<16;j++) acc[j] = fdot2(hp, w[j], acc[j]);
        }
        #pragma unroll
        for (int jj=0;jj<8;jj++){
          int f0 = g*16 + 2*jj;
          cvp[o][g*8+jj] = pk_rne(fmaxf(acc[2*jj]+bc[f0],0.f),
                                  fmaxf(acc[2*jj+1]+bc[f0+1],0.f));
        }
      }
      __syncthreads();
      // S8: alpha
      if (tid < 256){
        float s=0.f;
        #pragma unroll
        for (int p=0;p<16;p++) s = fdot2(cvp[tid][p], wpair[p], s);
        alpha[tid] = sigm(s);
      }
      __syncthreads();
      // S9: v partials (32 o-chunks x 32 f) -> gp as float[1024]
      {
        int og = tid>>5, f = tid&31;
        uint hi = f&1; int fp=f>>1;
        float s=0.f;
        #pragma unroll
        for (int oo=0;oo<8;oo++){
          int oa = og*8+oo;
          s += alpha[oa]*f16sel(cvp[oa][fp], hi);
        }
        ((float*)gp)[og*32+f] = s;
      }
      __syncthreads();
      // S10: v finish -> APR[256..271]
      if (tid<32){
        float v=0.f;
        #pragma unroll
        for (int q=0;q<32;q++) v += ((float*)gp)[q*32+tid];
        float vn = __shfl_xor(v,1);
        if (!(tid&1)){
          uint h,l; pk_hl(fmaxf(v,0.f), fmaxf(vn,0.f), h,l);
          APR2[256+(tid>>1)]=make_uint2(h,l);
        }
      }
      __syncthreads();
      // S12: Wl2 partials  (g: kpp in [g*34, g*34+34))
      {
        float ahi=0.f, alo=0.f;
        const uint4* wp = Wl24 + (size_t)(g*34)*256 + o;
        const uint4* ap = (const uint4*)(APR2 + g*68);
        #pragma unroll 4
        for (int kpp=0;kpp<34;kpp++){
          uint4 w = wp[0]; wp += 256;
          uint4 A = ap[kpp];
          ahi = fdot2(A.x, w.x, ahi); alo = fdot2(A.y, w.x, alo); alo = fdot2(A.x, w.y, alo);
          ahi = fdot2(A.z, w.z, ahi); alo = fdot2(A.w, w.z, alo); alo = fdot2(A.z, w.w, alo);
        }
        p4[g][o] = ahi + alo*LO_SCALE;
      }
      __syncthreads();
      // S13 (merged with nh combine): APR = [ht raw | nh]; res write
      if (tid<128){ uint h,l; pk_hl(ht[2*tid], ht[2*tid+1], h,l); APR2[tid]=make_uint2(h,l); }
      else if (tid<256){
        int j=tid-128, o0=2*j, o1=o0+1;
        float n0 = p4[0][o0]+p4[1][o0]+p4[2][o0]+p4[3][o0]+bl2[o0];
        float n1 = p4[0][o1]+p4[1][o1]+p4[2][o1]+p4[3][o1]+bl2[o1];
        uint h,l; pk_hl(n0,n1,h,l); APR2[tid]=make_uint2(h,l);
        if (l==1){} // (placeholder no-op to keep structure clear)
        if (1){
          // res write only on inner layer l==1 — captured via lambda-free check below
        }
        // store nh to res when l==1 (l is loop var of outer scope)
        // handled just below with explicit flag
        p4[0][o0] = n0; p4[0][o1] = n1;   // stash combined nh for res write
      }
      __syncthreads();
      if (l==1 && tid>=128 && tid<256){
        int j=tid-128, o0=2*j, o1=o0+1;
        float* rr = res + (size_t)(t*128+b)*256;
        rr[o0] = p4[0][o0]; rr[o1] = p4[0][o1];
      }
      // S14: output partials
      {
        float ahi=0.f, alo=0.f;
        const uint4* wp = Wd4 + (size_t)(g*32)*256 + o;
        const uint4* ap = (const uint4*)(APR2 + g*64);
        #pragma unroll 4
        for (int kpp=0;kpp<32;kpp++){
          uint4 w = wp[0]; wp += 256;
          uint4 A = ap[kpp];
          ahi = fdot2(A.x, w.x, ahi); alo = fdot2(A.y, w.x, alo); alo = fdot2(A.x, w.y, alo);
          ahi = fdot2(A.z, w.z, ahi); alo = fdot2(A.w, w.z, alo); alo = fdot2(A.z, w.w, alo);
        }
        __syncthreads();           // ensure p4 nh-stash consumed before overwrite
        p4[g][o] = ahi + alo*LO_SCALE;
      }
      __syncthreads();
      // S15: next xi pairs; Hbuf ring append relu(output). APR[128..255] keeps nh.
      if (tid<128){
        int o0=2*tid, o1=o0+1;
        float u0 = p4[0][o0]+p4[1][o0]+p4[2][o0]+p4[3][o0]+bd[o0];
        float u1 = p4[0][o1]+p4[1][o1]+p4[2][o1]+p4[3][o1]+bd[o1];
        uint h,l; pk_hl(u0, u1, h, l);
        APR2[tid]=make_uint2(h,l);
        int s = base & 63, ps = s>>1; uint hb = (uint)(s&1);
        uint h0 = (uint)f16b(fmaxf(u0,0.f)), h1 = (uint)f16b(fmaxf(u1,0.f));
        uint old0 = Hp[ps][o0], old1 = Hp[ps][o1];
        Hp[ps][o0] = hb ? ((old0&0xFFFFu)|(h0<<16)) : ((old0&0xFFFF0000u)|h0);
        Hp[ps][o1] = hb ? ((old1&0xFFFFu)|(h1<<16)) : ((old1&0xFFFF0000u)|h1);
      }
      __syncthreads();
      base++;
    }
  }
}

// ---------- K3: out[b,c,h,t] = relu(res[t,b,h])*wend[c] + bend[c]  (float32) ----------
__global__ void k3(const float* __restrict__ res, const float* __restrict__ wend,
                   const float* __restrict__ bend, float* __restrict__ out)
{
  __shared__ float r2[64][257];
  int b = blockIdx.x, tid = threadIdx.x;
  for (int i = tid; i < 16384; i += 256){
    int t = i >> 8, h = i & 255;
    r2[t][h] = fmaxf(res[(size_t)(t*128+b)*256 + h], 0.f);
  }
  __syncthreads();
  int tt = tid & 63, hg = tid >> 6;
  for (int c=0;c<8;c++){
    float we = wend[c], be = bend[c];
    for (int hh=0;hh<64;hh++){
      int h = hg*64 + hh;
      out[((size_t)(b*8+c)*256 + h)*64 + tt] = r2[tt][h]*we + be;
    }
  }
}

// ---------- launch ----------
extern "C" __attribute__((visibility("default"), used))
void kernel_launch(void* const* d_in, const int* in_sizes, int n_in,
                   void* d_out, int out_size, void* d_ws, size_t ws_size,
                   hipStream_t stream)
{
  const float* x    = (const float*)d_in[0];
  const float* wst  = (const float*)d_in[1];
  const float* bst  = (const float*)d_in[2];
  const float* Wh   = (const float*)d_in[3];
  const float* bh   = (const float*)d_in[4];
  const float* Wih  = (const float*)d_in[5];
  const float* Whh  = (const float*)d_in[6];
  const float* bih  = (const float*)d_in[7];
  const float* bhh  = (const float*)d_in[8];
  const float* Wd   = (const float*)d_in[9];
  const float* bd   = (const float*)d_in[10];
  const float* Wc   = (const float*)d_in[11];
  const float* bc   = (const float*)d_in[12];
  const float* Wl1  = (const float*)d_in[13];
  const float* bl1  = (const float*)d_in[14];
  const float* Wl2  = (const float*)d_in[15];
  const float* bl2  = (const float*)d_in[16];
  const float* wend = (const float*)d_in[17];
  const float* bend = (const float*)d_in[18];

  char* ws = (char*)d_ws;
  uint4* Wd4   = (uint4*)(ws + 0);          // 524288 B
  uint4* Wc4hi = (uint4*)(ws + 524288);     // 1048576 B
  uint4* Wc4lo = (uint4*)(ws + 1572864);    // 1048576 B
  uint4* Wl24  = (uint4*)(ws + 2621440);    // 557056 B
  float* Wl1f  = (float*)(ws + 3178496);    // 65536 B
  uint*  Wcrot = (uint*) (ws + 3244032);    // 262144 B
  uint*  WhT2  = (uint*) (ws + 3506176);    // 131072 B
  float* bcomb = (float*)(ws + 3637248);    // 4096 B
  ushort* yT   = (ushort*)(ws + 3641344);   // 4194304 B
  float* xcon  = (float*)(ws + 7835648);    // 8388608 B
  float* res   = (float*)(ws + 16224256);   // 8388608 B -> end 24612864

  kPack<<<512, 256, 0, stream>>>(Wd, Wih, Whh, Wl1, Wl2, Wc, Wh, bih, bhh,
                                 Wd4, Wc4hi, Wc4lo, Wl24, Wl1f, Wcrot, WhT2, bcomb);
  k1a<<<dim3(128,4), 256, 0, stream>>>(x, wst, bst, yT);
  k1b<<<128, 256, 0, stream>>>((const uint*)yT, WhT2, bh, xcon);
  TPALSTM_17205638987874_kernel<<<128, 1024, 0, stream>>>(xcon, Wd4, Wc4hi, Wc4lo, Wl24,
                                                          Wl1f, Wcrot, bd, bcomb, bl1, bl2, bc, res);
  k3<<<128, 256, 0, stream>>>(res, wend, bend, (float*)d_out);
}